// Round 9
// baseline (911.449 us; speedup 1.0000x reference)
//
#include <hip/hip_runtime.h>
#include <hip/hip_bf16.h>
#include <math.h>

// Problem constants
#define BATCH 8
#define CDIM 512
#define XY 1024
#define NCTX 1024
#define HEADS 8
#define DHEAD 64
#define EINNER 512
#define E2 1024

#define SQRT_DIM 22.627416997969522f   // sqrt(512)
#define NEG_SL2E -0.18033688011112042f // -(1/8) * log2(e)

typedef short bf16x8 __attribute__((ext_vector_type(8)));
typedef float f32x4 __attribute__((ext_vector_type(4)));
typedef unsigned short u16;
typedef u16 ushort8v __attribute__((ext_vector_type(8)));
typedef u16 ushort4v __attribute__((ext_vector_type(4)));

__device__ __forceinline__ u16 f2bf(float x) {
    return __builtin_bit_cast(u16, __float2bfloat16(x));
}
__device__ __forceinline__ float bf2f(u16 h) {
    unsigned int u = ((unsigned int)h) << 16;
    return __builtin_bit_cast(float, u);
}
// single-instruction transcendentals (libm versions carry fixup sequences)
__device__ __forceinline__ float fast_sqrt(float x) {
    float r;
    asm("v_sqrt_f32 %0, %1" : "=v"(r) : "v"(x));
    return r;
}
__device__ __forceinline__ float fast_exp2(float x) {
    float r;
    asm("v_exp_f32 %0, %1" : "=v"(r) : "v"(x));
    return r;
}

// ---------------------------------------------------------------------------
// fmap prep: raw transpose-split fmT[b][xy][c] (hi/lo) + fscale[b][xy].
// ---------------------------------------------------------------------------
__global__ __launch_bounds__(256) void k_fmap_prep(const float* __restrict__ fmap,
                                                   u16* __restrict__ fmTh,
                                                   u16* __restrict__ fmTl,
                                                   float* __restrict__ fscale) {
    const int blk = blockIdx.x, b = blk >> 5, x0 = (blk & 31) * 32;
    const int xy = threadIdx.x & 31, cg = threadIdx.x >> 5;
    const float* p = fmap + (size_t)b * CDIM * XY + x0 + xy;
    u16* ph = fmTh + ((size_t)b * 1024 + x0 + xy) * 512 + cg * 64;
    u16* pl = fmTl + ((size_t)b * 1024 + x0 + xy) * 512 + cg * 64;
    float ss = 0.f;
#pragma unroll
    for (int ii = 0; ii < 8; ++ii) {
        ushort8v h8, l8;
#pragma unroll
        for (int j = 0; j < 8; ++j) {
            float v = p[(size_t)(cg * 64 + ii * 8 + j) * XY];
            ss = fmaf(v, v, ss);
            u16 hh = f2bf(v);
            h8[j] = hh;
            l8[j] = f2bf(v - bf2f(hh));
        }
        *(ushort8v*)(ph + ii * 8) = h8;
        *(ushort8v*)(pl + ii * 8) = l8;
    }
    __shared__ float red[8][33];
    red[cg][xy] = ss;
    __syncthreads();
    if (threadIdx.x < 32) {
        float s = red[0][xy] + red[1][xy] + red[2][xy] + red[3][xy]
                + red[4][xy] + red[5][xy] + red[6][xy] + red[7][xy];
        fscale[b * XY + x0 + xy] = SQRT_DIM / fmaxf(sqrtf(s), 1e-12f);
    }
}

// ---------------------------------------------------------------------------
__global__ __launch_bounds__(256) void k_ctx_scale(const float* __restrict__ ctx,
                                                   float* __restrict__ cscale) {
    int row = blockIdx.x * 4 + (threadIdx.x >> 6);
    int lane = threadIdx.x & 63;
    const float* p = ctx + (size_t)row * CDIM;
    float ss = 0.f;
#pragma unroll
    for (int k = 0; k < CDIM / 64; ++k) {
        float v = p[lane + 64 * k];
        ss = fmaf(v, v, ss);
    }
#pragma unroll
    for (int off = 32; off; off >>= 1) ss += __shfl_down(ss, off, 64);
    if (lane == 0) cscale[row] = SQRT_DIM / fmaxf(sqrtf(ss), 1e-12f);
}

// ---------------------------------------------------------------------------
__global__ __launch_bounds__(256) void k_wsplit(const float* __restrict__ src,
                                                const float* __restrict__ gamma,
                                                u16* __restrict__ dh,
                                                u16* __restrict__ dl, int n8) {
    int i = blockIdx.x * 256 + threadIdx.x;
    if (i >= n8) return;
    size_t base = (size_t)i * 8;
    int k0 = (int)(base & 511);
    float4 a = *(const float4*)(src + base);
    float4 b4 = *(const float4*)(src + base + 4);
    float v[8] = {a.x, a.y, a.z, a.w, b4.x, b4.y, b4.z, b4.w};
    if (gamma) {
        float4 g0 = *(const float4*)(gamma + k0);
        float4 g1 = *(const float4*)(gamma + k0 + 4);
        v[0] *= g0.x; v[1] *= g0.y; v[2] *= g0.z; v[3] *= g0.w;
        v[4] *= g1.x; v[5] *= g1.y; v[6] *= g1.z; v[7] *= g1.w;
    }
    ushort8v h8, l8;
#pragma unroll
    for (int j = 0; j < 8; ++j) {
        u16 hh = f2bf(v[j]);
        h8[j] = hh;
        l8[j] = f2bf(v[j] - bf2f(hh));
    }
    *(ushort8v*)(dh + base) = h8;
    *(ushort8v*)(dl + base) = l8;
}

// ---------------------------------------------------------------------------
// Q projection GEMM. D rows = xy (A = fmT), cols = e (B = wq_s).
// ---------------------------------------------------------------------------
__global__ __launch_bounds__(256, 4) void k_gemm_q(
    const u16* __restrict__ fmTh, const u16* __restrict__ fmTl,
    const u16* __restrict__ wqh, const u16* __restrict__ wql,
    const float* __restrict__ fscale,
    u16* __restrict__ qh_, u16* __restrict__ ql_, float* __restrict__ q2g) {
    const int b = blockIdx.z, h = blockIdx.y, xy0 = blockIdx.x * 64;
    const int t = threadIdx.x, w = t >> 6, lane = t & 63;
    const int c = lane & 15, g = lane >> 4;
    const u16* Ah = fmTh + ((size_t)b * 1024 + xy0 + 16 * w + c) * 512 + 8 * g;
    const u16* Al = fmTl + ((size_t)b * 1024 + xy0 + 16 * w + c) * 512 + 8 * g;
    const u16* Bh0 = wqh + ((size_t)(h * 64) + c) * 512 + 8 * g;
    const u16* Bl0 = wql + ((size_t)(h * 64) + c) * 512 + 8 * g;
    f32x4 acc[4] = {{0.f,0.f,0.f,0.f},{0.f,0.f,0.f,0.f},{0.f,0.f,0.f,0.f},{0.f,0.f,0.f,0.f}};
#pragma unroll 2
    for (int k0 = 0; k0 < 512; k0 += 32) {
        bf16x8 ah = *(const bf16x8*)(Ah + k0);
        bf16x8 al = *(const bf16x8*)(Al + k0);
#pragma unroll
        for (int ct = 0; ct < 4; ++ct) {
            bf16x8 bh_ = *(const bf16x8*)(Bh0 + (size_t)ct * 16 * 512 + k0);
            bf16x8 bl_ = *(const bf16x8*)(Bl0 + (size_t)ct * 16 * 512 + k0);
            acc[ct] = __builtin_amdgcn_mfma_f32_16x16x32_bf16(ah, bh_, acc[ct], 0, 0, 0);
            acc[ct] = __builtin_amdgcn_mfma_f32_16x16x32_bf16(ah, bl_, acc[ct], 0, 0, 0);
            acc[ct] = __builtin_amdgcn_mfma_f32_16x16x32_bf16(al, bh_, acc[ct], 0, 0, 0);
        }
    }
    const int bh = b * 8 + h;
    const float4 fs4 = *(const float4*)(fscale + b * 1024 + xy0 + 16 * w + 4 * g);
    const float fsr[4] = {fs4.x, fs4.y, fs4.z, fs4.w};
    float s2[4] = {0.f, 0.f, 0.f, 0.f};
#pragma unroll
    for (int ct = 0; ct < 4; ++ct)
#pragma unroll
        for (int r = 0; r < 4; ++r) {
            float v = acc[ct][r] * fsr[r];
            u16 hh = f2bf(v);
            size_t adr = ((size_t)bh * 1024 + xy0 + 16 * w + 4 * g + r) * 64 + 16 * ct + c;
            qh_[adr] = hh;
            ql_[adr] = f2bf(v - bf2f(hh));
            s2[r] = fmaf(v, v, s2[r]);
        }
#pragma unroll
    for (int r = 0; r < 4; ++r) {
        float s = s2[r];
        s += __shfl_xor(s, 1, 64);
        s += __shfl_xor(s, 2, 64);
        s += __shfl_xor(s, 4, 64);
        s += __shfl_xor(s, 8, 64);
        if (c == 0) q2g[(size_t)bh * 1024 + xy0 + 16 * w + 4 * g + r] = s;
    }
}

// ---------------------------------------------------------------------------
// KV projection GEMM. A = ctx rows n (f32 split on the fly); B = wkv_s.
// et<8: khi/klo[bh][n][d] + k2g.  et>=8: vthi/vtlo[bh][d][n] via wave-LDS.
// ---------------------------------------------------------------------------
__global__ __launch_bounds__(256, 4) void k_gemm_kv(
    const float* __restrict__ ctx, const u16* __restrict__ wkvh,
    const u16* __restrict__ wkvl, const float* __restrict__ cscale,
    u16* __restrict__ khi, u16* __restrict__ klo,
    u16* __restrict__ vthi, u16* __restrict__ vtlo, float* __restrict__ k2g) {
    const int b = blockIdx.z, et = blockIdx.y, n0 = blockIdx.x * 64;
    const int t = threadIdx.x, w = t >> 6, lane = t & 63;
    const int c = lane & 15, g = lane >> 4;
    __shared__ u16 vl[4][2][64][24];
    const float* Ap = ctx + ((size_t)b * 1024 + n0 + 16 * w + c) * 512 + 8 * g;
    const u16* Bh0 = wkvh + ((size_t)(et * 64) + c) * 512 + 8 * g;
    const u16* Bl0 = wkvl + ((size_t)(et * 64) + c) * 512 + 8 * g;
    f32x4 acc[4] = {{0.f,0.f,0.f,0.f},{0.f,0.f,0.f,0.f},{0.f,0.f,0.f,0.f},{0.f,0.f,0.f,0.f}};
#pragma unroll 2
    for (int k0 = 0; k0 < 512; k0 += 32) {
        float4 a0 = *(const float4*)(Ap + k0);
        float4 a1 = *(const float4*)(Ap + k0 + 4);
        float av[8] = {a0.x, a0.y, a0.z, a0.w, a1.x, a1.y, a1.z, a1.w};
        bf16x8 ah, al;
#pragma unroll
        for (int j = 0; j < 8; ++j) {
            u16 hh = f2bf(av[j]);
            ah[j] = (short)hh;
            al[j] = (short)f2bf(av[j] - bf2f(hh));
        }
#pragma unroll
        for (int ct = 0; ct < 4; ++ct) {
            bf16x8 bh_ = *(const bf16x8*)(Bh0 + (size_t)ct * 16 * 512 + k0);
            bf16x8 bl_ = *(const bf16x8*)(Bl0 + (size_t)ct * 16 * 512 + k0);
            acc[ct] = __builtin_amdgcn_mfma_f32_16x16x32_bf16(ah, bh_, acc[ct], 0, 0, 0);
            acc[ct] = __builtin_amdgcn_mfma_f32_16x16x32_bf16(ah, bl_, acc[ct], 0, 0, 0);
            acc[ct] = __builtin_amdgcn_mfma_f32_16x16x32_bf16(al, bh_, acc[ct], 0, 0, 0);
        }
    }
    const float4 cs4 = *(const float4*)(cscale + b * 1024 + n0 + 16 * w + 4 * g);
    const float csr[4] = {cs4.x, cs4.y, cs4.z, cs4.w};
    if (et < 8) {
        const int bh = b * 8 + et;
        float s2[4] = {0.f, 0.f, 0.f, 0.f};
#pragma unroll
        for (int ct = 0; ct < 4; ++ct)
#pragma unroll
            for (int r = 0; r < 4; ++r) {
                float v = acc[ct][r] * csr[r];
                u16 hh = f2bf(v);
                size_t adr = ((size_t)bh * 1024 + n0 + 16 * w + 4 * g + r) * 64 + 16 * ct + c;
                khi[adr] = hh;
                klo[adr] = f2bf(v - bf2f(hh));
                s2[r] = fmaf(v, v, s2[r]);
            }
#pragma unroll
        for (int r = 0; r < 4; ++r) {
            float s = s2[r];
            s += __shfl_xor(s, 1, 64);
            s += __shfl_xor(s, 2, 64);
            s += __shfl_xor(s, 4, 64);
            s += __shfl_xor(s, 8, 64);
            if (c == 0) k2g[(size_t)bh * 1024 + n0 + 16 * w + 4 * g + r] = s;
        }
    } else {
        const int h = et - 8, bh = b * 8 + h;
#pragma unroll
        for (int ct = 0; ct < 4; ++ct)
#pragma unroll
            for (int r = 0; r < 4; ++r) {
                float v = acc[ct][r] * csr[r];
                u16 hh = f2bf(v);
                vl[w][0][16 * ct + c][4 * g + r] = hh;
                vl[w][1][16 * ct + c][4 * g + r] = f2bf(v - bf2f(hh));
            }
        const int d = lane;
        ushort8v h0 = *(const ushort8v*)(&vl[w][0][d][0]);
        ushort8v h1 = *(const ushort8v*)(&vl[w][0][d][8]);
        ushort8v l0 = *(const ushort8v*)(&vl[w][1][d][0]);
        ushort8v l1 = *(const ushort8v*)(&vl[w][1][d][8]);
        size_t base = ((size_t)bh * 64 + d) * 1024 + n0 + 16 * w;
        *(ushort8v*)(vthi + base) = h0;
        *(ushort8v*)(vthi + base + 8) = h1;
        *(ushort8v*)(vtlo + base) = l0;
        *(ushort8v*)(vtlo + base + 8) = l1;
    }
}

// ---------------------------------------------------------------------------
// OUT projection GEMM. A = wout_s rows dim; B = aoT cols xy. C f32 [dim][xy].
// ---------------------------------------------------------------------------
__global__ __launch_bounds__(256, 4) void k_gemm_out(
    const u16* __restrict__ wouth, const u16* __restrict__ woutl,
    const u16* __restrict__ aoTh, const u16* __restrict__ aoTl,
    float* __restrict__ out) {
    const int b = blockIdx.z, m0 = blockIdx.y * 64, n0 = blockIdx.x * 64;
    const int t = threadIdx.x, w = t >> 6, lane = t & 63;
    const int c = lane & 15, g = lane >> 4;
    const u16* Ah = wouth + ((size_t)(m0 + 16 * w) + c) * 512 + 8 * g;
    const u16* Al = woutl + ((size_t)(m0 + 16 * w) + c) * 512 + 8 * g;
    const u16* Bh0 = aoTh + ((size_t)b * 1024 + n0 + c) * 512 + 8 * g;
    const u16* Bl0 = aoTl + ((size_t)b * 1024 + n0 + c) * 512 + 8 * g;
    f32x4 acc[4] = {{0.f,0.f,0.f,0.f},{0.f,0.f,0.f,0.f},{0.f,0.f,0.f,0.f},{0.f,0.f,0.f,0.f}};
#pragma unroll 2
    for (int k0 = 0; k0 < 512; k0 += 32) {
        bf16x8 ah = *(const bf16x8*)(Ah + k0);
        bf16x8 al = *(const bf16x8*)(Al + k0);
#pragma unroll
        for (int ct = 0; ct < 4; ++ct) {
            bf16x8 bh_ = *(const bf16x8*)(Bh0 + (size_t)ct * 16 * 512 + k0);
            bf16x8 bl_ = *(const bf16x8*)(Bl0 + (size_t)ct * 16 * 512 + k0);
            acc[ct] = __builtin_amdgcn_mfma_f32_16x16x32_bf16(ah, bh_, acc[ct], 0, 0, 0);
            acc[ct] = __builtin_amdgcn_mfma_f32_16x16x32_bf16(ah, bl_, acc[ct], 0, 0, 0);
            acc[ct] = __builtin_amdgcn_mfma_f32_16x16x32_bf16(al, bh_, acc[ct], 0, 0, 0);
        }
    }
#pragma unroll
    for (int ct = 0; ct < 4; ++ct)
#pragma unroll
        for (int r = 0; r < 4; ++r)
            out[((size_t)b * 512 + m0 + 16 * w + 4 * g + r) * 1024 + n0 + 16 * ct + c] =
                acc[ct][r];
}

// ---------------------------------------------------------------------------
// MFMA flash attention (real). Diet: 1-inst sqrt/exp2, loop-carried pointers.
// ---------------------------------------------------------------------------
__global__ __launch_bounds__(256, 4) void k_attn_mfma(
    const u16* __restrict__ q_h, const u16* __restrict__ q_l,
    const u16* __restrict__ khi, const u16* __restrict__ klo,
    const u16* __restrict__ vthi, const u16* __restrict__ vtlo,
    const float* __restrict__ q2g, const float* __restrict__ k2g,
    u16* __restrict__ aoTh, u16* __restrict__ aoTl) {
    const int bh = blockIdx.x;          // XCD-clustered
    const int i0 = blockIdx.y * 32;
    const int t = threadIdx.x;
    const int w = t >> 6;
    const int rg = w >> 1;
    const int jh = w & 1;
    const int lane = t & 63;
    const int c = lane & 15, g = lane >> 4;

    __shared__ __align__(16) char pool[4 * 4864];
    u16* psth = (u16*)(pool + w * 4864);   // [16][76]
    u16* pstl = psth + 16 * 76;
    __shared__ float msh[4][16];
    __shared__ float lsh[4][16];

    const int qrow = i0 + 16 * rg + c;
    const u16* qhp = q_h + ((size_t)bh * 1024 + qrow) * 64 + 8 * g;
    const u16* qlp = q_l + ((size_t)bh * 1024 + qrow) * 64 + 8 * g;
    bf16x8 qh[2], ql[2];
    qh[0] = *(const bf16x8*)(qhp);
    qh[1] = *(const bf16x8*)(qhp + 32);
    ql[0] = *(const bf16x8*)(qlp);
    ql[1] = *(const bf16x8*)(qlp + 32);
    const float q2c = q2g[(size_t)bh * 1024 + qrow];

    const int jbeg = jh * 512;
    // loop-carried pointers (imm-offset friendly)
    const u16* kh_p = khi + (size_t)bh * NCTX * 64 + (size_t)(jbeg + c) * 64 + 8 * g;
    const u16* kl_p = klo + (size_t)bh * NCTX * 64 + (size_t)(jbeg + c) * 64 + 8 * g;
    const u16* kh_p2 = kh_p + 2048;   // mm = 2,3 half
    const u16* kl_p2 = kl_p + 2048;
    const float* k2p = k2g + (size_t)bh * NCTX + jbeg + 4 * g;
    const u16* vh_p[4];
    const u16* vl_p[4];
#pragma unroll
    for (int dt = 0; dt < 4; ++dt) {
        vh_p[dt] = vthi + ((size_t)bh * 64 + 16 * dt + c) * NCTX + jbeg + 8 * g;
        vl_p[dt] = vtlo + ((size_t)bh * 64 + 16 * dt + c) * NCTX + jbeg + 8 * g;
    }

    f32x4 acc_o[4] = {{0.f,0.f,0.f,0.f},{0.f,0.f,0.f,0.f},{0.f,0.f,0.f,0.f},{0.f,0.f,0.f,0.f}};
    float m_run = -1e30f, l_run = 0.f;

    for (int it = 0; it < 8; ++it) {
        float s[4][4];
#pragma unroll
        for (int mm = 0; mm < 4; ++mm) {
            const u16* kr_h = (mm < 2 ? kh_p : kh_p2) + (mm & 1) * 1024;
            const u16* kr_l = (mm < 2 ? kl_p : kl_p2) + (mm & 1) * 1024;
            f32x4 acc = {0.f, 0.f, 0.f, 0.f};
#pragma unroll
            for (int kk = 0; kk < 2; ++kk) {
                bf16x8 kh_ = *(const bf16x8*)(kr_h + 32 * kk);
                bf16x8 kl_ = *(const bf16x8*)(kr_l + 32 * kk);
                acc = __builtin_amdgcn_mfma_f32_16x16x32_bf16(kh_, qh[kk], acc, 0, 0, 0);
                acc = __builtin_amdgcn_mfma_f32_16x16x32_bf16(kh_, ql[kk], acc, 0, 0, 0);
                acc = __builtin_amdgcn_mfma_f32_16x16x32_bf16(kl_, qh[kk], acc, 0, 0, 0);
            }
            const float4 kv4 = *(const float4*)(k2p + 16 * mm);
            const float k2a[4] = {kv4.x, kv4.y, kv4.z, kv4.w};
#pragma unroll
            for (int r = 0; r < 4; ++r) {
                float d2 = fmaf(-2.f, acc[r], q2c + k2a[r]);
                s[mm][r] = NEG_SL2E * fast_sqrt(fmaxf(d2, 0.f));
            }
        }
        float mt = s[0][0];
#pragma unroll
        for (int mm = 0; mm < 4; ++mm)
#pragma unroll
            for (int r = 0; r < 4; ++r) mt = fmaxf(mt, s[mm][r]);
        mt = fmaxf(mt, __shfl_xor(mt, 16, 64));
        mt = fmaxf(mt, __shfl_xor(mt, 32, 64));
        float mn = fmaxf(m_run, mt);
        float alpha = fast_exp2(m_run - mn);
        m_run = mn;
        float sum = 0.f;
#pragma unroll
        for (int mm = 0; mm < 4; ++mm)
#pragma unroll
            for (int r = 0; r < 4; ++r) {
                float e = fast_exp2(s[mm][r] - mn);
                s[mm][r] = e;
                sum += e;
            }
        sum += __shfl_xor(sum, 16, 64);
        sum += __shfl_xor(sum, 32, 64);
        l_run = l_run * alpha + sum;
#pragma unroll
        for (int dt = 0; dt < 4; ++dt)
#pragma unroll
            for (int r = 0; r < 4; ++r) acc_o[dt][r] *= alpha;

#pragma unroll
        for (int mm = 0; mm < 4; ++mm) {
            ushort4v h4, l4;
#pragma unroll
            for (int r = 0; r < 4; ++r) {
                u16 hh = f2bf(s[mm][r]);
                h4[r] = hh;
                l4[r] = f2bf(s[mm][r] - bf2f(hh));
            }
            *(ushort4v*)(psth + c * 76 + 16 * mm + 4 * g) = h4;
            *(ushort4v*)(pstl + c * 76 + 16 * mm + 4 * g) = l4;
        }
        bf16x8 ph[2], pl[2];
#pragma unroll
        for (int kk = 0; kk < 2; ++kk) {
            ph[kk] = *(const bf16x8*)(psth + c * 76 + 32 * kk + 8 * g);
            pl[kk] = *(const bf16x8*)(pstl + c * 76 + 32 * kk + 8 * g);
        }
#pragma unroll
        for (int dt = 0; dt < 4; ++dt) {
#pragma unroll
            for (int kk = 0; kk < 2; ++kk) {
                bf16x8 vh_ = *(const bf16x8*)(vh_p[dt] + 32 * kk);
                bf16x8 vl_ = *(const bf16x8*)(vl_p[dt] + 32 * kk);
                acc_o[dt] = __builtin_amdgcn_mfma_f32_16x16x32_bf16(vh_, ph[kk], acc_o[dt], 0, 0, 0);
                acc_o[dt] = __builtin_amdgcn_mfma_f32_16x16x32_bf16(vh_, pl[kk], acc_o[dt], 0, 0, 0);
                acc_o[dt] = __builtin_amdgcn_mfma_f32_16x16x32_bf16(vl_, ph[kk], acc_o[dt], 0, 0, 0);
            }
        }
        // advance loop-carried pointers by 64 keys
        kh_p += 4096; kl_p += 4096; kh_p2 += 4096; kl_p2 += 4096;
        k2p += 64;
#pragma unroll
        for (int dt = 0; dt < 4; ++dt) { vh_p[dt] += 64; vl_p[dt] += 64; }
    }

    float* pfw = (float*)(pool + w * 4864);   // [64 d][18]
#pragma unroll
    for (int dt = 0; dt < 4; ++dt)
#pragma unroll
        for (int r = 0; r < 4; ++r)
            pfw[(16 * dt + 4 * g + r) * 18 + c] = acc_o[dt][r];
    if (g == 0) { msh[w][c] = m_run; lsh[w][c] = l_run; }
    __syncthreads();

    {
        const int cq = t & 15, rgq = (t >> 4) & 1, dblk = t >> 5;
        const int wA = 2 * rgq, wB = wA + 1;
        const float m1 = msh[wA][cq], m2 = msh[wB][cq];
        const float l1 = lsh[wA][cq], l2 = lsh[wB][cq];
        const float M = fmaxf(m1, m2);
        const float e1 = fast_exp2(m1 - M), e2 = fast_exp2(m2 - M);
        const float inv = 1.f / (e1 * l1 + e2 * l2);
        const float w1 = e1 * inv, w2 = e2 * inv;
        const float* pA = (const float*)(pool + wA * 4864);
        const float* pB = (const float*)(pool + wB * 4864);
        const int b = bh >> 3, h = bh & 7;
        const int xy = i0 + 16 * rgq + cq;
        ushort8v h8, l8;
#pragma unroll
        for (int dd = 0; dd < 8; ++dd) {
            int d = dblk * 8 + dd;
            float o = w1 * pA[d * 18 + cq] + w2 * pB[d * 18 + cq];
            u16 hh = f2bf(o);
            h8[dd] = hh;
            l8[dd] = f2bf(o - bf2f(hh));
        }
        size_t adr = ((size_t)b * 1024 + xy) * 512 + h * 64 + dblk * 8;
        *(ushort8v*)(aoTh + adr) = h8;
        *(ushort8v*)(aoTl + adr) = l8;
    }
}

// ---------------------------------------------------------------------------
// DIAGNOSTIC skeleton: same grid/LDS/loads/MFMA as k_attn_mfma, but NO
// softmax / convert / LDS round-trip (P frags := Q frags; QK accs kept live
// via asm per rule "ablation-via-skip DCEs upstream ops"). Writes to scrap.
// Its dur splits the 260us floor: skel ~ full -> memory/MFMA-bound;
// skel << full -> the VALU middle is the elephant.
// ---------------------------------------------------------------------------
__global__ __launch_bounds__(256, 4) void k_attn_skel(
    const u16* __restrict__ q_h, const u16* __restrict__ q_l,
    const u16* __restrict__ khi, const u16* __restrict__ klo,
    const u16* __restrict__ vthi, const u16* __restrict__ vtlo,
    const float* __restrict__ q2g, const float* __restrict__ k2g,
    u16* __restrict__ aoTh, u16* __restrict__ aoTl) {
    const int bh = blockIdx.x;
    const int i0 = blockIdx.y * 32;
    const int t = threadIdx.x;
    const int w = t >> 6;
    const int rg = w >> 1;
    const int jh = w & 1;
    const int lane = t & 63;
    const int c = lane & 15, g = lane >> 4;

    __shared__ __align__(16) char pool[4 * 4864];   // same LDS footprint
    __shared__ float msh[4][16];
    __shared__ float lsh[4][16];

    const int qrow = i0 + 16 * rg + c;
    const u16* qhp = q_h + ((size_t)bh * 1024 + qrow) * 64 + 8 * g;
    const u16* qlp = q_l + ((size_t)bh * 1024 + qrow) * 64 + 8 * g;
    bf16x8 qh[2], ql[2];
    qh[0] = *(const bf16x8*)(qhp);
    qh[1] = *(const bf16x8*)(qhp + 32);
    ql[0] = *(const bf16x8*)(qlp);
    ql[1] = *(const bf16x8*)(qlp + 32);

    const int jbeg = jh * 512;
    const u16* kh_p = khi + (size_t)bh * NCTX * 64 + (size_t)(jbeg + c) * 64 + 8 * g;
    const u16* kl_p = klo + (size_t)bh * NCTX * 64 + (size_t)(jbeg + c) * 64 + 8 * g;
    const u16* kh_p2 = kh_p + 2048;
    const u16* kl_p2 = kl_p + 2048;
    const u16* vh_p[4];
    const u16* vl_p[4];
#pragma unroll
    for (int dt = 0; dt < 4; ++dt) {
        vh_p[dt] = vthi + ((size_t)bh * 64 + 16 * dt + c) * NCTX + jbeg + 8 * g;
        vl_p[dt] = vtlo + ((size_t)bh * 64 + 16 * dt + c) * NCTX + jbeg + 8 * g;
    }

    f32x4 acc_o[4] = {{0.f,0.f,0.f,0.f},{0.f,0.f,0.f,0.f},{0.f,0.f,0.f,0.f},{0.f,0.f,0.f,0.f}};

    for (int it = 0; it < 8; ++it) {
        // QK skeleton: loads + 12 MFMA, result kept live but unused
#pragma unroll
        for (int mm = 0; mm < 4; ++mm) {
            const u16* kr_h = (mm < 2 ? kh_p : kh_p2) + (mm & 1) * 1024;
            const u16* kr_l = (mm < 2 ? kl_p : kl_p2) + (mm & 1) * 1024;
            f32x4 acc = {0.f, 0.f, 0.f, 0.f};
#pragma unroll
            for (int kk = 0; kk < 2; ++kk) {
                bf16x8 kh_ = *(const bf16x8*)(kr_h + 32 * kk);
                bf16x8 kl_ = *(const bf16x8*)(kr_l + 32 * kk);
                acc = __builtin_amdgcn_mfma_f32_16x16x32_bf16(kh_, qh[kk], acc, 0, 0, 0);
                acc = __builtin_amdgcn_mfma_f32_16x16x32_bf16(kh_, ql[kk], acc, 0, 0, 0);
                acc = __builtin_amdgcn_mfma_f32_16x16x32_bf16(kl_, qh[kk], acc, 0, 0, 0);
            }
            asm volatile("" :: "v"(acc));   // keep QK live (anti-DCE)
        }
        // PV skeleton: loads + 12 MFMA; P frags := Q frags (no softmax/cvt/LDS)
#pragma unroll
        for (int dt = 0; dt < 4; ++dt) {
#pragma unroll
            for (int kk = 0; kk < 2; ++kk) {
                bf16x8 vh_ = *(const bf16x8*)(vh_p[dt] + 32 * kk);
                bf16x8 vl_ = *(const bf16x8*)(vl_p[dt] + 32 * kk);
                acc_o[dt] = __builtin_amdgcn_mfma_f32_16x16x32_bf16(vh_, qh[kk], acc_o[dt], 0, 0, 0);
                acc_o[dt] = __builtin_amdgcn_mfma_f32_16x16x32_bf16(vh_, ql[kk], acc_o[dt], 0, 0, 0);
                acc_o[dt] = __builtin_amdgcn_mfma_f32_16x16x32_bf16(vl_, qh[kk], acc_o[dt], 0, 0, 0);
            }
        }
        kh_p += 4096; kl_p += 4096; kh_p2 += 4096; kl_p2 += 4096;
#pragma unroll
        for (int dt = 0; dt < 4; ++dt) { vh_p[dt] += 64; vl_p[dt] += 64; }
    }

    // same-shape epilogue (keeps LDS live and output real) into scrap
    float* pfw = (float*)(pool + w * 4864);
#pragma unroll
    for (int dt = 0; dt < 4; ++dt)
#pragma unroll
        for (int r = 0; r < 4; ++r)
            pfw[(16 * dt + 4 * g + r) * 18 + c] = acc_o[dt][r];
    if (g == 0) { msh[w][c] = 0.f; lsh[w][c] = 1.f; }
    __syncthreads();
    {
        const int cq = t & 15, rgq = (t >> 4) & 1, dblk = t >> 5;
        const int wA = 2 * rgq, wB = wA + 1;
        const float l1 = lsh[wA][cq] + msh[wA][cq], l2 = lsh[wB][cq];
        const float inv = 1.f / (l1 + l2);
        const float* pA = (const float*)(pool + wA * 4864);
        const float* pB = (const float*)(pool + wB * 4864);
        const int b = bh >> 3, h = bh & 7;
        const int xy = i0 + 16 * rgq + cq;
        ushort8v h8, l8;
#pragma unroll
        for (int dd = 0; dd < 8; ++dd) {
            int d = dblk * 8 + dd;
            float o = inv * (pA[d * 18 + cq] + pB[d * 18 + cq]);
            u16 hh = f2bf(o);
            h8[dd] = hh;
            l8[dd] = f2bf(o - bf2f(hh));
        }
        size_t adr = ((size_t)b * 1024 + xy) * 512 + h * 64 + dblk * 8;
        *(ushort8v*)(aoTh + adr) = h8;
        *(ushort8v*)(aoTl + adr) = l8;
    }
}

// ---------------------------------------------------------------------------
extern "C" void kernel_launch(void* const* d_in, const int* in_sizes, int n_in,
                              void* d_out, int out_size, void* d_ws, size_t ws_size,
                              hipStream_t stream) {
    const float* fmap    = (const float*)d_in[0];
    const float* context = (const float*)d_in[1];
    const float* gfm     = (const float*)d_in[2];
    const float* gctx    = (const float*)d_in[3];
    const float* Wq      = (const float*)d_in[4];
    const float* Wkv     = (const float*)d_in[5];
    const float* Wout    = (const float*)d_in[6];
    float* out = (float*)d_out;

    // ws: four exact 16MiB regions with lifetime overlays (64MiB total).
    char* wsb = (char*)d_ws;
    u16* fmTh = (u16*)(wsb);                  // -> khi (after Q-GEMM) -> wout (after attn)
    u16* fmTl = (u16*)(wsb + (8u << 20));     // -> klo
    u16* khi  = fmTh;
    u16* klo  = fmTl;
    u16* vthi = (u16*)(wsb + (16u << 20));
    u16* vtlo = (u16*)(wsb + (24u << 20));
    u16* q_h  = (u16*)(wsb + (32u << 20));
    u16* q_l  = (u16*)(wsb + (40u << 20));
    u16* aoTh = (u16*)(wsb + (48u << 20));
    u16* aoTl = (u16*)(wsb + (56u << 20));
    u16* wouth = (u16*)(wsb);                 // written post-attn over dead khi
    u16* woutl = (u16*)(wsb + 524288 * 2);

    // d_out scratch (all dead before k_gemm_out fully overwrites d_out)
    u16* du = (u16*)d_out;
    u16* wkvh = du;
    u16* wkvl = du + 524288;
    u16* wqh  = du + 1048576;
    u16* wql  = du + 1310720;
    float* df = (float*)((char*)d_out + (4u << 20));
    float* q2g    = df;
    float* k2g    = df + 65536;
    float* fscale = df + 131072;
    float* cscale = df + 139264;

    k_fmap_prep<<<256, 256, 0, stream>>>(fmap, fmTh, fmTl, fscale);
    k_ctx_scale<<<2048, 256, 0, stream>>>(context, cscale);
    k_wsplit<<<128, 256, 0, stream>>>(Wq, gfm, wqh, wql, 512 * 512 / 8);
    k_wsplit<<<256, 256, 0, stream>>>(Wkv, gctx, wkvh, wkvl, 1024 * 512 / 8);

    k_gemm_q<<<dim3(16, 8, BATCH), 256, 0, stream>>>(
        fmTh, fmTl, wqh, wql, fscale, q_h, q_l, q2g);

    k_gemm_kv<<<dim3(16, 16, BATCH), 256, 0, stream>>>(
        context, wkvh, wkvl, cscale, khi, klo, vthi, vtlo, k2g);

    k_attn_mfma<<<dim3(64, 32), 256, 0, stream>>>(
        q_h, q_l, khi, klo, vthi, vtlo, q2g, k2g, aoTh, aoTl);

    // DIAGNOSTIC: skeleton into scrap (q_h/q_l are dead after real attention)
    k_attn_skel<<<dim3(64, 32), 256, 0, stream>>>(
        q_h, q_l, khi, klo, vthi, vtlo, q2g, k2g, q_h, q_l);

    k_wsplit<<<128, 256, 0, stream>>>(Wout, nullptr, wouth, woutl, 512 * 512 / 8);

    k_gemm_out<<<dim3(16, 8, BATCH), 256, 0, stream>>>(
        wouth, woutl, aoTh, aoTl, out);
}

// Round 10
// 653.297 us; speedup vs baseline: 1.3952x; 1.3952x over previous
//
#include <hip/hip_runtime.h>
#include <hip/hip_bf16.h>
#include <math.h>

// Problem constants
#define BATCH 8
#define CDIM 512
#define XY 1024
#define NCTX 1024
#define HEADS 8
#define DHEAD 64
#define EINNER 512
#define E2 1024

// Channel-decamped row strides (power-of-2 + 256B*odd):
//  - 512-u16 rows (1024B) -> 640 u16 = 1280B = 5*256B  (all 16 L2 channels)
//  - 1024-u16 V rows (2048B) -> 1152 u16 = 2304B = 9*256B
#define GSTR 640
#define VSTR 1152

#define SQRT_DIM 22.627416997969522f   // sqrt(512)
#define NEG_SL2E -0.18033688011112042f // -(1/8) * log2(e)

typedef short bf16x8 __attribute__((ext_vector_type(8)));
typedef float f32x4 __attribute__((ext_vector_type(4)));
typedef unsigned short u16;
typedef u16 ushort8v __attribute__((ext_vector_type(8)));
typedef u16 ushort4v __attribute__((ext_vector_type(4)));

__device__ __forceinline__ u16 f2bf(float x) {
    return __builtin_bit_cast(u16, __float2bfloat16(x));
}
__device__ __forceinline__ float bf2f(u16 h) {
    unsigned int u = ((unsigned int)h) << 16;
    return __builtin_bit_cast(float, u);
}
__device__ __forceinline__ float fast_sqrt(float x) {
    float r;
    asm("v_sqrt_f32 %0, %1" : "=v"(r) : "v"(x));
    return r;
}
__device__ __forceinline__ float fast_exp2(float x) {
    float r;
    asm("v_exp_f32 %0, %1" : "=v"(r) : "v"(x));
    return r;
}

// ---------------------------------------------------------------------------
// fmap prep: transpose-split fmT[b][xy][GSTR] (hi/lo) + fscale[b][xy].
// ---------------------------------------------------------------------------
__global__ __launch_bounds__(256) void k_fmap_prep(const float* __restrict__ fmap,
                                                   u16* __restrict__ fmTh,
                                                   u16* __restrict__ fmTl,
                                                   float* __restrict__ fscale) {
    const int blk = blockIdx.x, b = blk >> 5, x0 = (blk & 31) * 32;
    const int xy = threadIdx.x & 31, cg = threadIdx.x >> 5;
    const float* p = fmap + (size_t)b * CDIM * XY + x0 + xy;
    u16* ph = fmTh + ((size_t)b * 1024 + x0 + xy) * GSTR + cg * 64;
    u16* pl = fmTl + ((size_t)b * 1024 + x0 + xy) * GSTR + cg * 64;
    float ss = 0.f;
#pragma unroll
    for (int ii = 0; ii < 8; ++ii) {
        ushort8v h8, l8;
#pragma unroll
        for (int j = 0; j < 8; ++j) {
            float v = p[(size_t)(cg * 64 + ii * 8 + j) * XY];
            ss = fmaf(v, v, ss);
            u16 hh = f2bf(v);
            h8[j] = hh;
            l8[j] = f2bf(v - bf2f(hh));
        }
        *(ushort8v*)(ph + ii * 8) = h8;
        *(ushort8v*)(pl + ii * 8) = l8;
    }
    __shared__ float red[8][33];
    red[cg][xy] = ss;
    __syncthreads();
    if (threadIdx.x < 32) {
        float s = red[0][xy] + red[1][xy] + red[2][xy] + red[3][xy]
                + red[4][xy] + red[5][xy] + red[6][xy] + red[7][xy];
        fscale[b * XY + x0 + xy] = SQRT_DIM / fmaxf(sqrtf(s), 1e-12f);
    }
}

// ---------------------------------------------------------------------------
// ctx prep: split ctx rows to bf16 hi/lo with GSTR padding + cscale[b*n].
// 4 rows per block; lane covers elements lane*8..lane*8+7 (coalesced).
// ---------------------------------------------------------------------------
__global__ __launch_bounds__(256) void k_ctx_prep(const float* __restrict__ ctx,
                                                  u16* __restrict__ ctxh,
                                                  u16* __restrict__ ctxl,
                                                  float* __restrict__ cscale) {
    const int row = blockIdx.x * 4 + (threadIdx.x >> 6);
    const int lane = threadIdx.x & 63;
    const float* p = ctx + (size_t)row * CDIM + lane * 8;
    float4 a0 = *(const float4*)(p);
    float4 a1 = *(const float4*)(p + 4);
    float v[8] = {a0.x, a0.y, a0.z, a0.w, a1.x, a1.y, a1.z, a1.w};
    float ss = 0.f;
    ushort8v h8, l8;
#pragma unroll
    for (int j = 0; j < 8; ++j) {
        ss = fmaf(v[j], v[j], ss);
        u16 hh = f2bf(v[j]);
        h8[j] = hh;
        l8[j] = f2bf(v[j] - bf2f(hh));
    }
    *(ushort8v*)(ctxh + (size_t)row * GSTR + lane * 8) = h8;
    *(ushort8v*)(ctxl + (size_t)row * GSTR + lane * 8) = l8;
#pragma unroll
    for (int off = 32; off; off >>= 1) ss += __shfl_down(ss, off, 64);
    if (lane == 0) cscale[row] = SQRT_DIM / fmaxf(sqrtf(ss), 1e-12f);
}

// ---------------------------------------------------------------------------
// weight split: dst rows GSTR-padded; src rows 512 f32; optional gamma[k].
// ---------------------------------------------------------------------------
__global__ __launch_bounds__(256) void k_wsplit(const float* __restrict__ src,
                                                const float* __restrict__ gamma,
                                                u16* __restrict__ dh,
                                                u16* __restrict__ dl, int n8) {
    int i = blockIdx.x * 256 + threadIdx.x;
    if (i >= n8) return;
    size_t base = (size_t)i * 8;
    int k0 = (int)(base & 511);
    size_t row = base >> 9;
    float4 a = *(const float4*)(src + base);
    float4 b4 = *(const float4*)(src + base + 4);
    float v[8] = {a.x, a.y, a.z, a.w, b4.x, b4.y, b4.z, b4.w};
    if (gamma) {
        float4 g0 = *(const float4*)(gamma + k0);
        float4 g1 = *(const float4*)(gamma + k0 + 4);
        v[0] *= g0.x; v[1] *= g0.y; v[2] *= g0.z; v[3] *= g0.w;
        v[4] *= g1.x; v[5] *= g1.y; v[6] *= g1.z; v[7] *= g1.w;
    }
    ushort8v h8, l8;
#pragma unroll
    for (int j = 0; j < 8; ++j) {
        u16 hh = f2bf(v[j]);
        h8[j] = hh;
        l8[j] = f2bf(v[j] - bf2f(hh));
    }
    size_t dst = row * GSTR + k0;
    *(ushort8v*)(dh + dst) = h8;
    *(ushort8v*)(dl + dst) = l8;
}

// ---------------------------------------------------------------------------
// Q projection GEMM. A = fmT (GSTR rows), B = wq_s (GSTR rows).
// Out: q_h/q_l [bh][xy][64] (in d_out) + q2g.
// ---------------------------------------------------------------------------
__global__ __launch_bounds__(256, 4) void k_gemm_q(
    const u16* __restrict__ fmTh, const u16* __restrict__ fmTl,
    const u16* __restrict__ wqh, const u16* __restrict__ wql,
    const float* __restrict__ fscale,
    u16* __restrict__ qh_, u16* __restrict__ ql_, float* __restrict__ q2g) {
    const int b = blockIdx.z, h = blockIdx.y, xy0 = blockIdx.x * 64;
    const int t = threadIdx.x, w = t >> 6, lane = t & 63;
    const int c = lane & 15, g = lane >> 4;
    const u16* Ah = fmTh + ((size_t)b * 1024 + xy0 + 16 * w + c) * GSTR + 8 * g;
    const u16* Al = fmTl + ((size_t)b * 1024 + xy0 + 16 * w + c) * GSTR + 8 * g;
    const u16* Bh0 = wqh + ((size_t)(h * 64) + c) * GSTR + 8 * g;
    const u16* Bl0 = wql + ((size_t)(h * 64) + c) * GSTR + 8 * g;
    f32x4 acc[4] = {{0.f,0.f,0.f,0.f},{0.f,0.f,0.f,0.f},{0.f,0.f,0.f,0.f},{0.f,0.f,0.f,0.f}};
#pragma unroll 2
    for (int k0 = 0; k0 < 512; k0 += 32) {
        bf16x8 ah = *(const bf16x8*)(Ah + k0);
        bf16x8 al = *(const bf16x8*)(Al + k0);
#pragma unroll
        for (int ct = 0; ct < 4; ++ct) {
            bf16x8 bh_ = *(const bf16x8*)(Bh0 + (size_t)ct * 16 * GSTR + k0);
            bf16x8 bl_ = *(const bf16x8*)(Bl0 + (size_t)ct * 16 * GSTR + k0);
            acc[ct] = __builtin_amdgcn_mfma_f32_16x16x32_bf16(ah, bh_, acc[ct], 0, 0, 0);
            acc[ct] = __builtin_amdgcn_mfma_f32_16x16x32_bf16(ah, bl_, acc[ct], 0, 0, 0);
            acc[ct] = __builtin_amdgcn_mfma_f32_16x16x32_bf16(al, bh_, acc[ct], 0, 0, 0);
        }
    }
    const int bh = b * 8 + h;
    const float4 fs4 = *(const float4*)(fscale + b * 1024 + xy0 + 16 * w + 4 * g);
    const float fsr[4] = {fs4.x, fs4.y, fs4.z, fs4.w};
    float s2[4] = {0.f, 0.f, 0.f, 0.f};
#pragma unroll
    for (int ct = 0; ct < 4; ++ct)
#pragma unroll
        for (int r = 0; r < 4; ++r) {
            float v = acc[ct][r] * fsr[r];
            u16 hh = f2bf(v);
            size_t adr = ((size_t)bh * 1024 + xy0 + 16 * w + 4 * g + r) * 64 + 16 * ct + c;
            qh_[adr] = hh;
            ql_[adr] = f2bf(v - bf2f(hh));
            s2[r] = fmaf(v, v, s2[r]);
        }
#pragma unroll
    for (int r = 0; r < 4; ++r) {
        float s = s2[r];
        s += __shfl_xor(s, 1, 64);
        s += __shfl_xor(s, 2, 64);
        s += __shfl_xor(s, 4, 64);
        s += __shfl_xor(s, 8, 64);
        if (c == 0) q2g[(size_t)bh * 1024 + xy0 + 16 * w + 4 * g + r] = s;
    }
}

// ---------------------------------------------------------------------------
// KV projection GEMM. A = ctx_s (pre-split, GSTR rows); B = wkv_s (GSTR rows).
// et<8: khi/klo[bh][n][64] + k2g.  et>=8: vthi/vtlo[bh][d][VSTR] via wave-LDS.
// ---------------------------------------------------------------------------
__global__ __launch_bounds__(256, 4) void k_gemm_kv(
    const u16* __restrict__ ctxh, const u16* __restrict__ ctxl,
    const u16* __restrict__ wkvh, const u16* __restrict__ wkvl,
    const float* __restrict__ cscale,
    u16* __restrict__ khi, u16* __restrict__ klo,
    u16* __restrict__ vthi, u16* __restrict__ vtlo, float* __restrict__ k2g) {
    const int b = blockIdx.z, et = blockIdx.y, n0 = blockIdx.x * 64;
    const int t = threadIdx.x, w = t >> 6, lane = t & 63;
    const int c = lane & 15, g = lane >> 4;
    __shared__ u16 vl[4][2][64][24];
    const u16* Ah = ctxh + ((size_t)b * 1024 + n0 + 16 * w + c) * GSTR + 8 * g;
    const u16* Al = ctxl + ((size_t)b * 1024 + n0 + 16 * w + c) * GSTR + 8 * g;
    const u16* Bh0 = wkvh + ((size_t)(et * 64) + c) * GSTR + 8 * g;
    const u16* Bl0 = wkvl + ((size_t)(et * 64) + c) * GSTR + 8 * g;
    f32x4 acc[4] = {{0.f,0.f,0.f,0.f},{0.f,0.f,0.f,0.f},{0.f,0.f,0.f,0.f},{0.f,0.f,0.f,0.f}};
#pragma unroll 2
    for (int k0 = 0; k0 < 512; k0 += 32) {
        bf16x8 ah = *(const bf16x8*)(Ah + k0);
        bf16x8 al = *(const bf16x8*)(Al + k0);
#pragma unroll
        for (int ct = 0; ct < 4; ++ct) {
            bf16x8 bh_ = *(const bf16x8*)(Bh0 + (size_t)ct * 16 * GSTR + k0);
            bf16x8 bl_ = *(const bf16x8*)(Bl0 + (size_t)ct * 16 * GSTR + k0);
            acc[ct] = __builtin_amdgcn_mfma_f32_16x16x32_bf16(ah, bh_, acc[ct], 0, 0, 0);
            acc[ct] = __builtin_amdgcn_mfma_f32_16x16x32_bf16(ah, bl_, acc[ct], 0, 0, 0);
            acc[ct] = __builtin_amdgcn_mfma_f32_16x16x32_bf16(al, bh_, acc[ct], 0, 0, 0);
        }
    }
    const float4 cs4 = *(const float4*)(cscale + b * 1024 + n0 + 16 * w + 4 * g);
    const float csr[4] = {cs4.x, cs4.y, cs4.z, cs4.w};
    if (et < 8) {
        const int bh = b * 8 + et;
        float s2[4] = {0.f, 0.f, 0.f, 0.f};
#pragma unroll
        for (int ct = 0; ct < 4; ++ct)
#pragma unroll
            for (int r = 0; r < 4; ++r) {
                float v = acc[ct][r] * csr[r];
                u16 hh = f2bf(v);
                size_t adr = ((size_t)bh * 1024 + n0 + 16 * w + 4 * g + r) * 64 + 16 * ct + c;
                khi[adr] = hh;
                klo[adr] = f2bf(v - bf2f(hh));
                s2[r] = fmaf(v, v, s2[r]);
            }
#pragma unroll
        for (int r = 0; r < 4; ++r) {
            float s = s2[r];
            s += __shfl_xor(s, 1, 64);
            s += __shfl_xor(s, 2, 64);
            s += __shfl_xor(s, 4, 64);
            s += __shfl_xor(s, 8, 64);
            if (c == 0) k2g[(size_t)bh * 1024 + n0 + 16 * w + 4 * g + r] = s;
        }
    } else {
        const int h = et - 8, bh = b * 8 + h;
#pragma unroll
        for (int ct = 0; ct < 4; ++ct)
#pragma unroll
            for (int r = 0; r < 4; ++r) {
                float v = acc[ct][r] * csr[r];
                u16 hh = f2bf(v);
                vl[w][0][16 * ct + c][4 * g + r] = hh;
                vl[w][1][16 * ct + c][4 * g + r] = f2bf(v - bf2f(hh));
            }
        const int d = lane;
        ushort8v h0 = *(const ushort8v*)(&vl[w][0][d][0]);
        ushort8v h1 = *(const ushort8v*)(&vl[w][0][d][8]);
        ushort8v l0 = *(const ushort8v*)(&vl[w][1][d][0]);
        ushort8v l1 = *(const ushort8v*)(&vl[w][1][d][8]);
        size_t base = ((size_t)bh * 64 + d) * VSTR + n0 + 16 * w;
        *(ushort8v*)(vthi + base) = h0;
        *(ushort8v*)(vthi + base + 8) = h1;
        *(ushort8v*)(vtlo + base) = l0;
        *(ushort8v*)(vtlo + base + 8) = l1;
    }
}

// ---------------------------------------------------------------------------
// OUT projection GEMM. A = wout_s (GSTR rows); B = aoT (GSTR rows). C f32.
// ---------------------------------------------------------------------------
__global__ __launch_bounds__(256, 4) void k_gemm_out(
    const u16* __restrict__ wouth, const u16* __restrict__ woutl,
    const u16* __restrict__ aoTh, const u16* __restrict__ aoTl,
    float* __restrict__ out) {
    const int b = blockIdx.z, m0 = blockIdx.y * 64, n0 = blockIdx.x * 64;
    const int t = threadIdx.x, w = t >> 6, lane = t & 63;
    const int c = lane & 15, g = lane >> 4;
    const u16* Ah = wouth + ((size_t)(m0 + 16 * w) + c) * GSTR + 8 * g;
    const u16* Al = woutl + ((size_t)(m0 + 16 * w) + c) * GSTR + 8 * g;
    const u16* Bh0 = aoTh + ((size_t)b * 1024 + n0 + c) * GSTR + 8 * g;
    const u16* Bl0 = aoTl + ((size_t)b * 1024 + n0 + c) * GSTR + 8 * g;
    f32x4 acc[4] = {{0.f,0.f,0.f,0.f},{0.f,0.f,0.f,0.f},{0.f,0.f,0.f,0.f},{0.f,0.f,0.f,0.f}};
#pragma unroll 2
    for (int k0 = 0; k0 < 512; k0 += 32) {
        bf16x8 ah = *(const bf16x8*)(Ah + k0);
        bf16x8 al = *(const bf16x8*)(Al + k0);
#pragma unroll
        for (int ct = 0; ct < 4; ++ct) {
            bf16x8 bh_ = *(const bf16x8*)(Bh0 + (size_t)ct * 16 * GSTR + k0);
            bf16x8 bl_ = *(const bf16x8*)(Bl0 + (size_t)ct * 16 * GSTR + k0);
            acc[ct] = __builtin_amdgcn_mfma_f32_16x16x32_bf16(ah, bh_, acc[ct], 0, 0, 0);
            acc[ct] = __builtin_amdgcn_mfma_f32_16x16x32_bf16(ah, bl_, acc[ct], 0, 0, 0);
            acc[ct] = __builtin_amdgcn_mfma_f32_16x16x32_bf16(al, bh_, acc[ct], 0, 0, 0);
        }
    }
#pragma unroll
    for (int ct = 0; ct < 4; ++ct)
#pragma unroll
        for (int r = 0; r < 4; ++r)
            out[((size_t)b * 512 + m0 + 16 * w + 4 * g + r) * 1024 + n0 + 16 * ct + c] =
                acc[ct][r];
}

// ---------------------------------------------------------------------------
// MFMA flash attention. Identical compute to R9; V reads at VSTR (decamped),
// aoT writes at GSTR. XCD-clustered grid (bh fastest).
// ---------------------------------------------------------------------------
__global__ __launch_bounds__(256, 4) void k_attn_mfma(
    const u16* __restrict__ q_h, const u16* __restrict__ q_l,
    const u16* __restrict__ khi, const u16* __restrict__ klo,
    const u16* __restrict__ vthi, const u16* __restrict__ vtlo,
    const float* __restrict__ q2g, const float* __restrict__ k2g,
    u16* __restrict__ aoTh, u16* __restrict__ aoTl) {
    const int bh = blockIdx.x;
    const int i0 = blockIdx.y * 32;
    const int t = threadIdx.x;
    const int w = t >> 6;
    const int rg = w >> 1;
    const int jh = w & 1;
    const int lane = t & 63;
    const int c = lane & 15, g = lane >> 4;

    __shared__ __align__(16) char pool[4 * 4864];
    u16* psth = (u16*)(pool + w * 4864);   // [16][76]
    u16* pstl = psth + 16 * 76;
    __shared__ float msh[4][16];
    __shared__ float lsh[4][16];

    const int qrow = i0 + 16 * rg + c;
    const u16* qhp = q_h + ((size_t)bh * 1024 + qrow) * 64 + 8 * g;
    const u16* qlp = q_l + ((size_t)bh * 1024 + qrow) * 64 + 8 * g;
    bf16x8 qh[2], ql[2];
    qh[0] = *(const bf16x8*)(qhp);
    qh[1] = *(const bf16x8*)(qhp + 32);
    ql[0] = *(const bf16x8*)(qlp);
    ql[1] = *(const bf16x8*)(qlp + 32);
    const float q2c = q2g[(size_t)bh * 1024 + qrow];

    const int jbeg = jh * 512;
    const u16* kh_p = khi + (size_t)bh * NCTX * 64 + (size_t)(jbeg + c) * 64 + 8 * g;
    const u16* kl_p = klo + (size_t)bh * NCTX * 64 + (size_t)(jbeg + c) * 64 + 8 * g;
    const u16* kh_p2 = kh_p + 2048;
    const u16* kl_p2 = kl_p + 2048;
    const float* k2p = k2g + (size_t)bh * NCTX + jbeg + 4 * g;
    const u16* vh_p[4];
    const u16* vl_p[4];
#pragma unroll
    for (int dt = 0; dt < 4; ++dt) {
        vh_p[dt] = vthi + ((size_t)bh * 64 + 16 * dt + c) * VSTR + jbeg + 8 * g;
        vl_p[dt] = vtlo + ((size_t)bh * 64 + 16 * dt + c) * VSTR + jbeg + 8 * g;
    }

    f32x4 acc_o[4] = {{0.f,0.f,0.f,0.f},{0.f,0.f,0.f,0.f},{0.f,0.f,0.f,0.f},{0.f,0.f,0.f,0.f}};
    float m_run = -1e30f, l_run = 0.f;

    for (int it = 0; it < 8; ++it) {
        float s[4][4];
#pragma unroll
        for (int mm = 0; mm < 4; ++mm) {
            const u16* kr_h = (mm < 2 ? kh_p : kh_p2) + (mm & 1) * 1024;
            const u16* kr_l = (mm < 2 ? kl_p : kl_p2) + (mm & 1) * 1024;
            f32x4 acc = {0.f, 0.f, 0.f, 0.f};
#pragma unroll
            for (int kk = 0; kk < 2; ++kk) {
                bf16x8 kh_ = *(const bf16x8*)(kr_h + 32 * kk);
                bf16x8 kl_ = *(const bf16x8*)(kr_l + 32 * kk);
                acc = __builtin_amdgcn_mfma_f32_16x16x32_bf16(kh_, qh[kk], acc, 0, 0, 0);
                acc = __builtin_amdgcn_mfma_f32_16x16x32_bf16(kh_, ql[kk], acc, 0, 0, 0);
                acc = __builtin_amdgcn_mfma_f32_16x16x32_bf16(kl_, qh[kk], acc, 0, 0, 0);
            }
            const float4 kv4 = *(const float4*)(k2p + 16 * mm);
            const float k2a[4] = {kv4.x, kv4.y, kv4.z, kv4.w};
#pragma unroll
            for (int r = 0; r < 4; ++r) {
                float d2 = fmaf(-2.f, acc[r], q2c + k2a[r]);
                s[mm][r] = NEG_SL2E * fast_sqrt(fmaxf(d2, 0.f));
            }
        }
        float mt = s[0][0];
#pragma unroll
        for (int mm = 0; mm < 4; ++mm)
#pragma unroll
            for (int r = 0; r < 4; ++r) mt = fmaxf(mt, s[mm][r]);
        mt = fmaxf(mt, __shfl_xor(mt, 16, 64));
        mt = fmaxf(mt, __shfl_xor(mt, 32, 64));
        float mn = fmaxf(m_run, mt);
        float alpha = fast_exp2(m_run - mn);
        m_run = mn;
        float sum = 0.f;
#pragma unroll
        for (int mm = 0; mm < 4; ++mm)
#pragma unroll
            for (int r = 0; r < 4; ++r) {
                float e = fast_exp2(s[mm][r] - mn);
                s[mm][r] = e;
                sum += e;
            }
        sum += __shfl_xor(sum, 16, 64);
        sum += __shfl_xor(sum, 32, 64);
        l_run = l_run * alpha + sum;
#pragma unroll
        for (int dt = 0; dt < 4; ++dt)
#pragma unroll
            for (int r = 0; r < 4; ++r) acc_o[dt][r] *= alpha;

#pragma unroll
        for (int mm = 0; mm < 4; ++mm) {
            ushort4v h4, l4;
#pragma unroll
            for (int r = 0; r < 4; ++r) {
                u16 hh = f2bf(s[mm][r]);
                h4[r] = hh;
                l4[r] = f2bf(s[mm][r] - bf2f(hh));
            }
            *(ushort4v*)(psth + c * 76 + 16 * mm + 4 * g) = h4;
            *(ushort4v*)(pstl + c * 76 + 16 * mm + 4 * g) = l4;
        }
        bf16x8 ph[2], pl[2];
#pragma unroll
        for (int kk = 0; kk < 2; ++kk) {
            ph[kk] = *(const bf16x8*)(psth + c * 76 + 32 * kk + 8 * g);
            pl[kk] = *(const bf16x8*)(pstl + c * 76 + 32 * kk + 8 * g);
        }
#pragma unroll
        for (int dt = 0; dt < 4; ++dt) {
#pragma unroll
            for (int kk = 0; kk < 2; ++kk) {
                bf16x8 vh_ = *(const bf16x8*)(vh_p[dt] + 32 * kk);
                bf16x8 vl_ = *(const bf16x8*)(vl_p[dt] + 32 * kk);
                acc_o[dt] = __builtin_amdgcn_mfma_f32_16x16x32_bf16(vh_, ph[kk], acc_o[dt], 0, 0, 0);
                acc_o[dt] = __builtin_amdgcn_mfma_f32_16x16x32_bf16(vh_, pl[kk], acc_o[dt], 0, 0, 0);
                acc_o[dt] = __builtin_amdgcn_mfma_f32_16x16x32_bf16(vl_, ph[kk], acc_o[dt], 0, 0, 0);
            }
        }
        kh_p += 4096; kl_p += 4096; kh_p2 += 4096; kl_p2 += 4096;
        k2p += 64;
#pragma unroll
        for (int dt = 0; dt < 4; ++dt) { vh_p[dt] += 64; vl_p[dt] += 64; }
    }

    float* pfw = (float*)(pool + w * 4864);   // [64 d][18]
#pragma unroll
    for (int dt = 0; dt < 4; ++dt)
#pragma unroll
        for (int r = 0; r < 4; ++r)
            pfw[(16 * dt + 4 * g + r) * 18 + c] = acc_o[dt][r];
    if (g == 0) { msh[w][c] = m_run; lsh[w][c] = l_run; }
    __syncthreads();

    {
        const int cq = t & 15, rgq = (t >> 4) & 1, dblk = t >> 5;
        const int wA = 2 * rgq, wB = wA + 1;
        const float m1 = msh[wA][cq], m2 = msh[wB][cq];
        const float l1 = lsh[wA][cq], l2 = lsh[wB][cq];
        const float M = fmaxf(m1, m2);
        const float e1 = fast_exp2(m1 - M), e2 = fast_exp2(m2 - M);
        const float inv = 1.f / (e1 * l1 + e2 * l2);
        const float w1 = e1 * inv, w2 = e2 * inv;
        const float* pA = (const float*)(pool + wA * 4864);
        const float* pB = (const float*)(pool + wB * 4864);
        const int b = bh >> 3, h = bh & 7;
        const int xy = i0 + 16 * rgq + cq;
        ushort8v h8, l8;
#pragma unroll
        for (int dd = 0; dd < 8; ++dd) {
            int d = dblk * 8 + dd;
            float o = w1 * pA[d * 18 + cq] + w2 * pB[d * 18 + cq];
            u16 hh = f2bf(o);
            h8[dd] = hh;
            l8[dd] = f2bf(o - bf2f(hh));
        }
        size_t adr = ((size_t)b * 1024 + xy) * GSTR + h * 64 + dblk * 8;
        *(ushort8v*)(aoTh + adr) = h8;
        *(ushort8v*)(aoTl + adr) = l8;
    }
}

// ---------------------------------------------------------------------------
extern "C" void kernel_launch(void* const* d_in, const int* in_sizes, int n_in,
                              void* d_out, int out_size, void* d_ws, size_t ws_size,
                              hipStream_t stream) {
    const float* fmap    = (const float*)d_in[0];
    const float* context = (const float*)d_in[1];
    const float* gfm     = (const float*)d_in[2];
    const float* gctx    = (const float*)d_in[3];
    const float* Wq      = (const float*)d_in[4];
    const float* Wkv     = (const float*)d_in[5];
    const float* Wout    = (const float*)d_in[6];
    float* out = (float*)d_out;

    // ws layout (62.3 MiB total, < proven 64.06 MiB):
    //  R0 [0,10MiB):   fmTh -> khi -> wouth(+woutl at +1MiB)
    //  R1 [10,20):     fmTl -> klo
    //  R2 [20,29):     vthi (VSTR rows, 9 MiB)
    //  R3 [29,38):     vtlo
    //  R4 [38,48):     ctxh -> aoTh
    //  R5 [48,58):     ctxl -> aoTl
    //  R6 [58,..):     wq/wkv splits + q2g/k2g/fscale/cscale
    char* wsb = (char*)d_ws;
    u16* fmTh = (u16*)(wsb);
    u16* fmTl = (u16*)(wsb + (10u << 20));
    u16* khi  = fmTh;
    u16* klo  = fmTl;
    u16* wouth = fmTh;                          // post-attn, khi dead
    u16* woutl = (u16*)(wsb + (1u << 20));
    u16* vthi = (u16*)(wsb + (20u << 20));
    u16* vtlo = (u16*)(wsb + (29u << 20));
    u16* ctxh = (u16*)(wsb + (38u << 20));
    u16* ctxl = (u16*)(wsb + (48u << 20));
    u16* aoTh = ctxh;                           // attn output over dead ctx split
    u16* aoTl = ctxl;
    char* r6 = wsb + (58u << 20);
    u16* wqh  = (u16*)(r6);                     // 512*GSTR u16 = 0.625 MiB
    u16* wql  = (u16*)(r6 + 655360);
    u16* wkvh = (u16*)(r6 + 1310720);           // 1024*GSTR u16 = 1.25 MiB
    u16* wkvl = (u16*)(r6 + 2621440);
    float* q2g    = (float*)(r6 + 3932160);     // 256 KiB
    float* k2g    = q2g + 65536;                // 256 KiB
    float* fscale = k2g + 65536;                // 32 KiB
    float* cscale = fscale + 8192;              // 32 KiB

    // d_out scratch: q_h [0,8MiB), q_l [8,16MiB); dead before k_gemm_out.
    u16* q_h = (u16*)d_out;
    u16* q_l = q_h + 4194304;

    k_fmap_prep<<<256, 256, 0, stream>>>(fmap, fmTh, fmTl, fscale);
    k_ctx_prep<<<2048, 256, 0, stream>>>(context, ctxh, ctxl, cscale);
    k_wsplit<<<128, 256, 0, stream>>>(Wq, gfm, wqh, wql, 512 * 512 / 8);
    k_wsplit<<<256, 256, 0, stream>>>(Wkv, gctx, wkvh, wkvl, 1024 * 512 / 8);

    k_gemm_q<<<dim3(16, 8, BATCH), 256, 0, stream>>>(
        fmTh, fmTl, wqh, wql, fscale, q_h, q_l, q2g);

    k_gemm_kv<<<dim3(16, 16, BATCH), 256, 0, stream>>>(
        ctxh, ctxl, wkvh, wkvl, cscale, khi, klo, vthi, vtlo, k2g);

    k_attn_mfma<<<dim3(64, 32), 256, 0, stream>>>(
        q_h, q_l, khi, klo, vthi, vtlo, q2g, k2g, aoTh, aoTl);

    k_wsplit<<<128, 256, 0, stream>>>(Wout, nullptr, wouth, woutl, 512 * 512 / 8);

    k_gemm_out<<<dim3(16, 8, BATCH), 256, 0, stream>>>(
        wouth, woutl, aoTh, aoTl, out);
}